// Round 14
// baseline (446.026 us; speedup 1.0000x reference)
//
#include <hip/hip_runtime.h>
#include <hip/hip_bf16.h>

#define NN 50000
#define EE 640000
#define GG 512
#define NPB 16      // nodes per k_edge block
#define NLB 3125    // logical k_edge blocks (50000/16)
#define CPX 391     // logical blocks per XCD chunk (8*391 = 3128 >= 3125)
#define CAPD 48     // fixed slots per node in ed (P(deg>=48) ~ 1e-14 for Poisson(12.8))
#define CCAP 48     // cached entries per node in LDS (slot 0 = self-loop)
#define WSTR 772    // shw row stride: 772 % 32 = 4 -> heads land in distinct banks
#define NBKT 391    // dst buckets of 128 nodes (50000/128 -> 391)
#define BCAP 512    // records per bucket instance (expected 205, +20 sigma)
#define PLA 625     // phase-A blocks (EE / 4 / 256)

typedef unsigned int uint;
typedef __attribute__((ext_vector_type(8))) short short8;
typedef __attribute__((ext_vector_type(4))) float floatx4;

__device__ inline float2 bf2f(uint u) {
    return make_float2(__uint_as_float(u << 16), __uint_as_float(u & 0xffff0000u));
}
__device__ inline uint packbf(float a, float b) {
    __hip_bfloat162 t;
    t.x = __float2bfloat16(a);
    t.y = __float2bfloat16(b);
    return *(uint*)&t;
}
__device__ inline uint bfbits(float v) {            // bf16 bit pattern (RNE), low 16
    __hip_bfloat16 t = __float2bfloat16(v);
    return (uint)*(unsigned short*)&t;
}
__device__ inline float bflo(uint u) { return __uint_as_float(u << 16); }
__device__ inline float bfhi(uint u) { return __uint_as_float(u & 0xffff0000u); }

// merged prep. Blocks 0..PLA-1: phase-A bucket append, 4 edges/thread, single sweep.
// Bucket = dst>>7; instance = blk&7 (XCD-local cursor+data lines -> appends to
// consecutive positions fill 64B lines inside ONE L2 before writeback = no RMW amp).
// Then: block PLA -> Mt + zero bns4; +1..+128 -> WbT convert; rest -> node encoder.
__global__ __launch_bounds__(256) void k_prep(const float* __restrict__ lin_e_w,
                                              const float* __restrict__ att_e,
                                              const float* __restrict__ encW,
                                              const float* __restrict__ encB,
                                              const float* __restrict__ W,
                                              const float* __restrict__ x,
                                              const float* __restrict__ nodeW,
                                              const float* __restrict__ nodeB,
                                              const int* __restrict__ src,
                                              const int* __restrict__ dst,
                                              const float* __restrict__ edge_attr,
                                              int* __restrict__ bcnt, uint* __restrict__ bkt,
                                              float* __restrict__ Mt, float* __restrict__ bns4,
                                              uint* __restrict__ WbT, uint* __restrict__ hb) {
    int tid = threadIdx.x;
    int blk = blockIdx.x;
    if (blk < PLA) {
        int inst = blk & 7;
        int e0 = (blk * 256 + tid) * 4;           // EE = 625*256*4 exactly
        int4 d4 = *(const int4*)(dst + e0);
        int4 s4 = *(const int4*)(src + e0);
        const float4* ar4 = (const float4*)(edge_attr + (size_t)e0 * 3);
        float4 q0 = ar4[0], q1 = ar4[1], q2 = ar4[2];
        const float* a = &q0.x;
        int dd[4] = {d4.x, d4.y, d4.z, d4.w};
        int ss[4] = {s4.x, s4.y, s4.z, s4.w};
#pragma unroll
        for (int i = 0; i < 4; i++) {
            int d = dd[i];
            int b = d >> 7;
            uint w0 = (uint)(ss[i] & 0xffff) | ((uint)(d & 127) << 16);
            uint w1 = bfbits(a[3 * i]) | (bfbits(a[3 * i + 1]) << 16);
            uint w2 = bfbits(a[3 * i + 2]);
            int p = atomicAdd(&bcnt[inst * NBKT + b], 1);
            if (p < BCAP)
                *(uint4*)(bkt + ((size_t)(inst * NBKT + b) * BCAP + p) * 4) =
                    make_uint4(w0, w1, w2, 0u);
        }
    } else if (blk == PLA) {
        __shared__ float we[128 * 16];
        for (int idx = tid; idx < 2048; idx += 256) {
            int k = idx >> 4, lh = idx & 15, l = lh >> 2, h = lh & 3;
            const float* wrow = lin_e_w + l * 16384 + k * 128 + h * 32;
            const float* arow = att_e + l * 128 + h * 32;
            float acc = 0.f;
#pragma unroll
            for (int c = 0; c < 32; c++) acc += wrow[c] * arow[c];
            we[k * 16 + lh] = acc;
        }
        for (int i = tid; i < 4 * 8 * 256; i += 256) bns4[i] = 0.f;
        __syncthreads();
        if (tid < 64) {
            int lh = tid >> 2, r = tid & 3;
            float acc = 0.f;
            for (int k = 0; k < 128; k++) {
                float a = (r < 3) ? encW[r * 128 + k] : encB[k];
                acc += a * we[k * 16 + lh];
            }
            Mt[lh * 4 + r] = acc;
        }
    } else if (blk <= PLA + 128) {
        int idx = (blk - PLA - 1) * 256 + tid;    // < 4*128*64 = 32768
        int l = idx >> 13, rem = idx & 8191, n = rem >> 6, u = rem & 63;
        const float* Wl = W + l * 16384;
        WbT[idx] = packbf(Wl[(2 * u) * 128 + n], Wl[(2 * u + 1) * 128 + n]);
    } else {
        int idx = (blk - PLA - 129) * 256 + tid;  // < NN*64 = 3,200,000
        int n = idx >> 6, c0 = (idx & 63) * 2;
        float a0 = nodeB[c0], a1 = nodeB[c0 + 1];
        const float* xr = x + n * 8;
#pragma unroll
        for (int f = 0; f < 8; f++) {
            a0 += xr[f] * nodeW[f * 128 + c0];
            a1 += xr[f] * nodeW[f * 128 + c0 + 1];
        }
        hb[idx] = packbf(a0, a1);
    }
}

// phase B: one block per bucket (128 nodes). Records -> LDS slot array via LDS-atomic
// cursors, then streamed to ed fully coalesced; cnt written directly (no global atomics).
__global__ __launch_bounds__(256) void k_place2(const int* __restrict__ bcnt,
                                                const uint* __restrict__ bkt,
                                                uint* __restrict__ ed, int* __restrict__ cnt) {
    __shared__ uint2 slots[128 * CAPD];           // 49 KB
    __shared__ int lcnt[128];
    int tid = threadIdx.x, b = blockIdx.x;
    int node0 = b * 128;
    int nInB = NN - node0; if (nInB > 128) nInB = 128;
    if (tid < 128) lcnt[tid] = 0;
    __syncthreads();
#pragma unroll 1
    for (int j = 0; j < 8; j++) {
        int n = bcnt[j * NBKT + b]; if (n > BCAP) n = BCAP;
        const uint* base = bkt + (size_t)(j * NBKT + b) * BCAP * 4;
        for (int i = tid; i < n; i += 256) {
            uint4 r = *(const uint4*)(base + (size_t)i * 4);
            int dstl = (r.x >> 16) & 127;
            int p = atomicAdd(&lcnt[dstl], 1);
            if (p < CAPD)
                slots[dstl * CAPD + p] = make_uint2((r.x & 0xffffu) | (r.y << 16),
                                                    (r.y >> 16) | (r.z << 16));
        }
    }
    __syncthreads();
    int total = nInB * CAPD;
    uint* d0 = ed + (size_t)node0 * CAPD * 2;
    for (int idx = tid; idx < total; idx += 256)
        *(uint2*)(d0 + (size_t)idx * 2) = slots[idx];
    if (tid < nInB) cnt[node0 + tid] = lcnt[tid];
}

// MFMA GEMM with fused BN+ReLU+residual prologue (modes: 0 = read hb as-is (layer 0);
// 1 = h = relu(bn(gout)), write hb; 2 = h = hb + relu(bn(gout)), write hb).
__global__ __launch_bounds__(256) void k_gemm(uint* __restrict__ hb, const uint* __restrict__ gout,
                                              const float* __restrict__ bns,
                                              const float* __restrict__ gamma,
                                              const float* __restrict__ beta,
                                              const uint* __restrict__ WbT,
                                              const float* __restrict__ a_src, const float* __restrict__ a_dst,
                                              uint* __restrict__ xpb, float* __restrict__ s_arr,
                                              float* __restrict__ d_arr, int mode) {
    __shared__ __align__(16) uint Bl[128 * 68];
    __shared__ __align__(16) uint Ah[64 * 66];
    __shared__ float sc[128], sf[128];
    int tid = threadIdx.x;
    int rowBase = blockIdx.x * 64;
    for (int idx = tid; idx < 2048; idx += 256) {
        int n = idx >> 4, u4 = idx & 15;
        uint4 v = *(const uint4*)(WbT + n * 64 + u4 * 4);
        *(uint4*)(&Bl[n * 68 + u4 * 4]) = v;
    }
    if (mode && tid < 128) {
        float s = 0.f, q = 0.f;
#pragma unroll
        for (int k = 0; k < 8; k++) { s += bns[k * 256 + tid]; q += bns[k * 256 + 128 + tid]; }
        float mu = s * (1.f / NN);
        float var = q * (1.f / NN) - mu * mu;
        float iv = rsqrtf(fmaxf(var, 0.f) + 1e-5f);
        float a = gamma[tid] * iv;
        sc[tid] = a;
        sf[tid] = beta[tid] - mu * a;
    }
    __syncthreads();
    if (mode) {
        for (int idx = tid; idx < 4096; idx += 256) {
            int row = idx >> 6, u = idx & 63;
            int gr = rowBase + row;
            uint pk = 0;
            if (gr < NN) {
                float2 v = bf2f(gout[(size_t)gr * 64 + u]);
                int c0 = u * 2;
                float r0 = fmaxf(v.x * sc[c0] + sf[c0], 0.f);
                float r1 = fmaxf(v.y * sc[c0 + 1] + sf[c0 + 1], 0.f);
                if (mode == 2) {
                    float2 hp = bf2f(hb[(size_t)gr * 64 + u]);
                    r0 += hp.x; r1 += hp.y;
                }
                pk = packbf(r0, r1);
                hb[(size_t)gr * 64 + u] = pk;
            }
            Ah[row * 66 + u] = pk;
        }
        __syncthreads();
    }
    int lane = tid & 63, wv = tid >> 6;
    int ln15 = lane & 15, quad = lane >> 4;
    int rowL = wv * 16 + ln15;
    int rowA = rowBase + rowL;
    short8 af[4];
    if (mode) {
#pragma unroll
        for (int c = 0; c < 4; c++)
            af[c] = *(const short8*)((const short*)&Ah[rowL * 66] + c * 32 + quad * 8);
    } else {
        int rowAc = rowA < NN ? rowA : 0;
#pragma unroll
        for (int c = 0; c < 4; c++)
            af[c] = *(const short8*)((const short*)hb + (size_t)rowAc * 128 + c * 32 + quad * 8);
    }
    floatx4 acc[8];
#pragma unroll
    for (int t = 0; t < 8; t++) acc[t] = (floatx4){0.f, 0.f, 0.f, 0.f};
#pragma unroll
    for (int c = 0; c < 4; c++) {
#pragma unroll
        for (int t = 0; t < 8; t++) {
            short8 bf = *(const short8*)((const short*)&Bl[(16 * t + ln15) * 68] + c * 32 + quad * 8);
            acc[t] = __builtin_amdgcn_mfma_f32_16x16x32_bf16(af[c], bf, acc[t], 0, 0, 0);
        }
    }
#pragma unroll
    for (int t = 0; t < 8; t++) {
#pragma unroll
        for (int r = 0; r < 4; r++) {
            float v = acc[t][r];
            float vhi = __shfl_xor(v, 1);
            int grow = rowBase + wv * 16 + quad * 4 + r;
            if (!(ln15 & 1) && grow < NN)
                xpb[(size_t)grow * 64 + 8 * t + (ln15 >> 1)] = packbf(v, vhi);
        }
    }
    float asl[4], ash[4], adl[4], adh[4];
#pragma unroll
    for (int hh = 0; hh < 4; hh++) {
        asl[hh] = a_src[hh * 32 + ln15]; ash[hh] = a_src[hh * 32 + 16 + ln15];
        adl[hh] = a_dst[hh * 32 + ln15]; adh[hh] = a_dst[hh * 32 + 16 + ln15];
    }
#pragma unroll
    for (int r = 0; r < 4; r++) {
        float s0 = acc[0][r] * asl[0] + acc[1][r] * ash[0];
        float s1 = acc[2][r] * asl[1] + acc[3][r] * ash[1];
        float s2 = acc[4][r] * asl[2] + acc[5][r] * ash[2];
        float s3 = acc[6][r] * asl[3] + acc[7][r] * ash[3];
        float d0 = acc[0][r] * adl[0] + acc[1][r] * adh[0];
        float d1 = acc[2][r] * adl[1] + acc[3][r] * adh[1];
        float d2 = acc[4][r] * adl[2] + acc[5][r] * adh[2];
        float d3 = acc[6][r] * adl[3] + acc[7][r] * adh[3];
#pragma unroll
        for (int off = 1; off < 16; off <<= 1) {
            s0 += __shfl_xor(s0, off); s1 += __shfl_xor(s1, off);
            s2 += __shfl_xor(s2, off); s3 += __shfl_xor(s3, off);
            d0 += __shfl_xor(d0, off); d1 += __shfl_xor(d1, off);
            d2 += __shfl_xor(d2, off); d3 += __shfl_xor(d3, off);
        }
        int grow = rowBase + wv * 16 + quad * 4 + r;
        if (ln15 == 0 && grow < NN) {
            *(float4*)(s_arr + grow * 4) = make_float4(s0, s1, s2, s3);
            *(float4*)(d_arr + grow * 4) = make_float4(d0, d1, d2, d3);
        }
    }
}

// fused segment softmax + aggregation + BN-stat partials, v6 (8-byte slot records).
__global__ __launch_bounds__(256) void k_edge(const int* __restrict__ cnt, const uint* __restrict__ ed,
                                              const float* __restrict__ Mt,
                                              const float* __restrict__ s_arr, const float* __restrict__ d_arr,
                                              const uint* __restrict__ xpb, uint* __restrict__ outb,
                                              float* __restrict__ bns, int layer) {
    __shared__ int kc_sh[NPB];
    __shared__ float d4c[NPB][4];
    __shared__ __align__(16) float shw[4][WSTR];   // per-node stripes of CCAP entries
    __shared__ int shs[NPB * CCAP];
    int tid = threadIdx.x;
    int lb = (blockIdx.x & 7) * CPX + (blockIdx.x >> 3);
    if (lb >= NLB) return;
    int nb0 = lb * NPB;
    if (tid < NPB) {
        int c = cnt[nb0 + tid];
        kc_sh[tid] = c < CAPD ? c : CAPD;
    }
    if (tid < NPB * 4)
        d4c[tid >> 2][tid & 3] = d_arr[(size_t)(nb0 + (tid >> 2)) * 4 + (tid & 3)];
    float4 mt0 = *(const float4*)(Mt + (layer * 4 + 0) * 4);
    float4 mt1 = *(const float4*)(Mt + (layer * 4 + 1) * 4);
    float4 mt2 = *(const float4*)(Mt + (layer * 4 + 2) * 4);
    float4 mt3 = *(const float4*)(Mt + (layer * 4 + 3) * 4);
    __syncthreads();
    // ---- pass 1: ni = tid>>4 (node stripe), sub = tid&15
    {
        int ni = tid >> 4, sub = tid & 15;
        int node = nb0 + ni;
        int k = kc_sh[ni];
        float as0 = 0.f, as1 = 0.f, as2 = 0.f;
        float dv0 = d4c[ni][0], dv1 = d4c[ni][1], dv2 = d4c[ni][2], dv3 = d4c[ni][3];
        for (int j = sub; j < k; j += 16) {
            uint2 r = *(const uint2*)(ed + ((size_t)node * CAPD + j) * 2);
            int sv = r.x & 0xffff;
            float a0 = bfhi(r.x), a1 = bflo(r.y), a2 = bfhi(r.y);
            as0 += a0; as1 += a1; as2 += a2;
            float4 s4 = *(const float4*)(s_arr + (size_t)sv * 4);
            float e_0 = a0 * mt0.x + a1 * mt0.y + a2 * mt0.z + mt0.w;
            float e_1 = a0 * mt1.x + a1 * mt1.y + a2 * mt1.z + mt1.w;
            float e_2 = a0 * mt2.x + a1 * mt2.y + a2 * mt2.z + mt2.w;
            float e_3 = a0 * mt3.x + a1 * mt3.y + a2 * mt3.z + mt3.w;
            float al0 = s4.x + dv0 + e_0; al0 = al0 > 0.f ? al0 : 0.2f * al0;
            float al1 = s4.y + dv1 + e_1; al1 = al1 > 0.f ? al1 : 0.2f * al1;
            float al2 = s4.z + dv2 + e_2; al2 = al2 > 0.f ? al2 : 0.2f * al2;
            float al3 = s4.w + dv3 + e_3; al3 = al3 > 0.f ? al3 : 0.2f * al3;
            if (j < CCAP - 1) {
                int ls = ni * CCAP + 1 + j;
                shs[ls] = sv;
                shw[0][ls] = __expf(al0);
                shw[1][ls] = __expf(al1);
                shw[2][ls] = __expf(al2);
                shw[3][ls] = __expf(al3);
            }
        }
#pragma unroll
        for (int off = 8; off; off >>= 1) {
            as0 += __shfl_xor(as0, off, 16);
            as1 += __shfl_xor(as1, off, 16);
            as2 += __shfl_xor(as2, off, 16);
        }
        if (sub == 0) {
            float inv = 1.f / fmaxf((float)k, 1.f);
            float m0 = as0 * inv, m1 = as1 * inv, m2 = as2 * inv;
            float wf = k > 0 ? 1.f : 0.f;
            float4 sl = *(const float4*)(s_arr + (size_t)node * 4);
            float e_0 = m0 * mt0.x + m1 * mt0.y + m2 * mt0.z + wf * mt0.w;
            float e_1 = m0 * mt1.x + m1 * mt1.y + m2 * mt1.z + wf * mt1.w;
            float e_2 = m0 * mt2.x + m1 * mt2.y + m2 * mt2.z + wf * mt2.w;
            float e_3 = m0 * mt3.x + m1 * mt3.y + m2 * mt3.z + wf * mt3.w;
            float al0 = sl.x + dv0 + e_0; al0 = al0 > 0.f ? al0 : 0.2f * al0;
            float al1 = sl.y + dv1 + e_1; al1 = al1 > 0.f ? al1 : 0.2f * al1;
            float al2 = sl.z + dv2 + e_2; al2 = al2 > 0.f ? al2 : 0.2f * al2;
            float al3 = sl.w + dv3 + e_3; al3 = al3 > 0.f ? al3 : 0.2f * al3;
            int ls = ni * CCAP;
            shs[ls] = node;
            shw[0][ls] = __expf(al0);
            shw[1][ls] = __expf(al1);
            shw[2][ls] = __expf(al2);
            shw[3][ls] = __expf(al3);
        }
    }
    __syncthreads();
    // ---- pass 2: wave per node group
    int wv = tid >> 6, lane = tid & 63, hh = lane >> 4;
    float4 mth = hh == 0 ? mt0 : hh == 1 ? mt1 : hh == 2 ? mt2 : mt3;
    float bs0 = 0.f, bs1 = 0.f, bq0 = 0.f, bq1 = 0.f;
#pragma unroll
    for (int q = 0; q < 4; q++) {
        int ni = wv * 4 + q;
        int node = nb0 + ni;
        int k = kc_sh[ni];
        int cached = 1 + (k < CCAP - 1 ? k : CCAP - 1);
        int base = ni * CCAP;
        float acc0 = 0.f, acc1 = 0.f, z = 0.f;
        int j = 0;
        for (; j + 8 <= cached; j += 8) {
            float w[8]; int sv[8]; uint xv[8];
#pragma unroll
            for (int u = 0; u < 8; u++) { w[u] = shw[hh][base + j + u]; sv[u] = shs[base + j + u]; }
#pragma unroll
            for (int u = 0; u < 8; u++) xv[u] = xpb[(size_t)sv[u] * 64 + lane];
#pragma unroll
            for (int u = 0; u < 8; u++) {
                z += w[u];
                float2 f = bf2f(xv[u]);
                acc0 += w[u] * f.x; acc1 += w[u] * f.y;
            }
        }
        for (; j + 4 <= cached; j += 4) {
            float w0 = shw[hh][base + j], w1 = shw[hh][base + j + 1];
            float w2 = shw[hh][base + j + 2], w3 = shw[hh][base + j + 3];
            int s0 = shs[base + j], s1 = shs[base + j + 1];
            int s2 = shs[base + j + 2], s3 = shs[base + j + 3];
            uint x0 = xpb[(size_t)s0 * 64 + lane];
            uint x1 = xpb[(size_t)s1 * 64 + lane];
            uint x2 = xpb[(size_t)s2 * 64 + lane];
            uint x3 = xpb[(size_t)s3 * 64 + lane];
            z += w0 + w1 + w2 + w3;
            float2 f0 = bf2f(x0), f1 = bf2f(x1), f2 = bf2f(x2), f3 = bf2f(x3);
            acc0 += w0 * f0.x + w1 * f1.x + w2 * f2.x + w3 * f3.x;
            acc1 += w0 * f0.y + w1 * f1.y + w2 * f2.y + w3 * f3.y;
        }
        for (; j < cached; j++) {
            float w = shw[hh][base + j];
            int sv = shs[base + j];
            z += w;
            float2 f = bf2f(xpb[(size_t)sv * 64 + lane]);
            acc0 += w * f.x; acc1 += w * f.y;
        }
        for (int je = CCAP - 1; je < k; je++) {    // overflow: plain edges (self-loop cached)
            uint2 r = *(const uint2*)(ed + ((size_t)node * CAPD + je) * 2);
            int sv = r.x & 0xffff;
            float a0 = bfhi(r.x), a1 = bflo(r.y), a2 = bfhi(r.y);
            float sva = s_arr[(size_t)sv * 4 + hh];
            float ev = a0 * mth.x + a1 * mth.y + a2 * mth.z + mth.w;
            float a = sva + d4c[ni][hh] + ev; a = a > 0.f ? a : 0.2f * a;
            float w = __expf(a);
            z += w;
            float2 f = bf2f(xpb[(size_t)sv * 64 + lane]);
            acc0 += w * f.x; acc1 += w * f.y;
        }
        float zi = 1.f / (z + 1e-16f);
        float o0 = acc0 * zi, o1 = acc1 * zi;
        outb[(size_t)node * 64 + lane] = packbf(o0, o1);
        bs0 += o0; bs1 += o1; bq0 += o0 * o0; bq1 += o1 * o1;
    }
    __syncthreads();
    float* scratch = &shw[0][0];
    scratch[wv * 256 + lane * 4 + 0] = bs0;
    scratch[wv * 256 + lane * 4 + 1] = bs1;
    scratch[wv * 256 + lane * 4 + 2] = bq0;
    scratch[wv * 256 + lane * 4 + 3] = bq1;
    __syncthreads();
    float v = scratch[tid] + scratch[256 + tid] + scratch[512 + tid] + scratch[768 + tid];
    int ln = tid >> 2, st = tid & 3;
    int gidx = (st < 2) ? (2 * ln + st) : (128 + 2 * ln + (st - 2));
    atomicAdd(&bns[(blockIdx.x & 7) * 256 + gidx], v);
}

// fused tail: final BN+ReLU+residual computed on the fly -> mean pool -> 3-layer MLP
__global__ __launch_bounds__(256) void k_tail(const uint* __restrict__ hb, const uint* __restrict__ gout,
                                              const float* __restrict__ bns,
                                              const float* __restrict__ gamma, const float* __restrict__ beta,
                                              const int* __restrict__ batch,
                                              const float* __restrict__ w1, const float* __restrict__ b1,
                                              const float* __restrict__ w2, const float* __restrict__ b2,
                                              const float* __restrict__ w3, const float* __restrict__ b3,
                                              float* __restrict__ out) {
    __shared__ float sc[128], sf[128];
    __shared__ float sh[2][256];
    __shared__ float gv[128], h1[128], h2[64];
    int tid = threadIdx.x;
    if (tid < 128) {
        float s = 0.f, q = 0.f;
#pragma unroll
        for (int k = 0; k < 8; k++) { s += bns[k * 256 + tid]; q += bns[k * 256 + 128 + tid]; }
        float mu = s * (1.f / NN);
        float var = q * (1.f / NN) - mu * mu;
        float iv = rsqrtf(fmaxf(var, 0.f) + 1e-5f);
        float a = gamma[tid] * iv;
        sc[tid] = a;
        sf[tid] = beta[tid] - mu * a;
    }
    __syncthreads();
    int gi = blockIdx.x;
    int t = tid & 63, rh = tid >> 6;
    int lo = 0, hi = NN;
    while (lo < hi) { int mid = (lo + hi) >> 1; if (batch[mid] < gi) lo = mid + 1; else hi = mid; }
    int start = lo;
    hi = NN;
    while (lo < hi) { int mid = (lo + hi) >> 1; if (batch[mid] < gi + 1) lo = mid + 1; else hi = mid; }
    int end = lo;
    float s0 = 0.f, s1 = 0.f;
    int c0 = t * 2;
    float a0c = sc[c0], a1c = sc[c0 + 1], f0c = sf[c0], f1c = sf[c0 + 1];
    for (int n = start + rh; n < end; n += 4) {
        float2 gvv = bf2f(gout[(size_t)n * 64 + t]);
        float2 hp = bf2f(hb[(size_t)n * 64 + t]);
        s0 += hp.x + fmaxf(gvv.x * a0c + f0c, 0.f);
        s1 += hp.y + fmaxf(gvv.y * a1c + f1c, 0.f);
    }
    sh[0][tid] = s0; sh[1][tid] = s1;
    __syncthreads();
    if (rh == 0) {
        float inv = 1.f / fmaxf((float)(end - start), 1.f);
        gv[2 * t]     = (sh[0][t] + sh[0][64 + t] + sh[0][128 + t] + sh[0][192 + t]) * inv;
        gv[2 * t + 1] = (sh[1][t] + sh[1][64 + t] + sh[1][128 + t] + sh[1][192 + t]) * inv;
    }
    __syncthreads();
    if (tid < 128) {
        float acc = b1[tid];
        for (int kk = 0; kk < 128; kk++) acc += gv[kk] * w1[kk * 128 + tid];
        h1[tid] = fmaxf(acc, 0.f);
    }
    __syncthreads();
    if (tid < 64) {
        float a2 = b2[tid];
        for (int kk = 0; kk < 128; kk++) a2 += h1[kk] * w2[kk * 64 + tid];
        h2[tid] = fmaxf(a2, 0.f);
    }
    __syncthreads();
    if (tid < 64) {
        float p = h2[tid] * w3[tid];
#pragma unroll
        for (int off = 32; off; off >>= 1) p += __shfl_xor(p, off);
        if (tid == 0) out[gi] = p + b3[0];
    }
}

extern "C" void kernel_launch(void* const* d_in, const int* in_sizes, int n_in,
                              void* d_out, int out_size, void* d_ws, size_t ws_size,
                              hipStream_t stream) {
    const float* x            = (const float*)d_in[0];
    const float* edge_attr    = (const float*)d_in[1];
    const int*   edge_index   = (const int*)d_in[2];
    const int*   batch        = (const int*)d_in[3];
    const float* enc_node_w   = (const float*)d_in[4];
    const float* enc_node_b   = (const float*)d_in[5];
    const float* enc_edge_w   = (const float*)d_in[6];
    const float* enc_edge_b   = (const float*)d_in[7];
    const float* gat_lin_w    = (const float*)d_in[8];
    const float* gat_att_src  = (const float*)d_in[9];
    const float* gat_att_dst  = (const float*)d_in[10];
    const float* gat_lin_edge = (const float*)d_in[11];
    const float* gat_att_edge = (const float*)d_in[12];
    // d_in[13] = gat_bias: constant per channel before training-mode BN -> cancels, unused
    const float* bn_gamma     = (const float*)d_in[14];
    const float* bn_beta      = (const float*)d_in[15];
    const float* fc1_w        = (const float*)d_in[16];
    const float* fc1_b        = (const float*)d_in[17];
    const float* fc2_w        = (const float*)d_in[18];
    const float* fc2_b        = (const float*)d_in[19];
    const float* fc3_w        = (const float*)d_in[20];
    const float* fc3_b        = (const float*)d_in[21];
    float* outv = (float*)d_out;

    char* ws = (char*)d_ws;
    size_t off = 0;
    auto alloc = [&](size_t bytes) -> void* {
        void* p = ws + off;
        off = (off + bytes + 255) & ~(size_t)255;
        return p;
    };
    uint*  hbv     = (uint*)alloc((size_t)NN * 64 * 4);     // bf16-packed residual stream h
    uint*  goutb   = (uint*)alloc((size_t)NN * 64 * 4);     // bf16-packed GAT output
    uint*  xpb     = (uint*)alloc((size_t)NN * 64 * 4);     // bf16-packed xp
    float* s_arr   = (float*)alloc((size_t)NN * 4 * 4);
    float* d_arr   = (float*)alloc((size_t)NN * 4 * 4);
    int*   cnt     = (int*)alloc((size_t)NN * 4);
    uint*  ed      = (uint*)alloc((size_t)NN * CAPD * 8);   // 8B slot records
    int*   bcnt    = (int*)alloc((size_t)8 * NBKT * 4);     // bucket cursors (8 XCD insts)
    uint*  bkt     = (uint*)alloc((size_t)8 * NBKT * BCAP * 16); // 16B bucket records
    uint*  WbT     = (uint*)alloc((size_t)4 * 128 * 64 * 4);
    float* Mt      = (float*)alloc(64 * 4);
    float* bns4    = (float*)alloc((size_t)4 * 8 * 256 * 4); // 4 layers x 8 XCD copies x 256
    (void)ws_size; (void)in_sizes; (void)n_in; (void)out_size;

    hipMemsetAsync(bcnt, 0, (size_t)8 * NBKT * 4, stream);

    const int* srce = edge_index;
    const int* dste = edge_index + EE;

    k_prep<<<PLA + 129 + (NN * 64) / 256, 256, 0, stream>>>(
        gat_lin_edge, gat_att_edge, enc_edge_w, enc_edge_b, gat_lin_w,
        x, enc_node_w, enc_node_b, srce, dste, edge_attr,
        bcnt, bkt, Mt, bns4, WbT, hbv);
    k_place2<<<NBKT, 256, 0, stream>>>(bcnt, bkt, ed, cnt);

    int gemmBlocks = (NN + 63) / 64;
    for (int l = 0; l < 4; l++) {
        int mode = (l == 0) ? 0 : (l == 1 ? 1 : 2);
        const float* bnsPrev = bns4 + (l - 1) * 2048;        // unused when mode==0
        k_gemm<<<gemmBlocks, 256, 0, stream>>>(hbv, goutb,
                                               mode ? bnsPrev : bns4,
                                               bn_gamma + (l ? (l - 1) * 128 : 0),
                                               bn_beta + (l ? (l - 1) * 128 : 0),
                                               WbT + l * 8192,
                                               gat_att_src + l * 128, gat_att_dst + l * 128,
                                               xpb, s_arr, d_arr, mode);
        k_edge<<<8 * CPX, 256, 0, stream>>>(cnt, ed, Mt, s_arr, d_arr, xpb, goutb,
                                            bns4 + l * 2048, l);
    }

    k_tail<<<GG, 256, 0, stream>>>(hbv, goutb, bns4 + 3 * 2048, bn_gamma + 3 * 128,
                                   bn_beta + 3 * 128, batch,
                                   fc1_w, fc1_b, fc2_w, fc2_b, fc3_w, fc3_b, outv);
}

// Round 15
// 422.114 us; speedup vs baseline: 1.0566x; 1.0566x over previous
//
#include <hip/hip_runtime.h>
#include <hip/hip_bf16.h>

#define NN 50000
#define EE 640000
#define GG 512
#define NPB 16      // nodes per k_edge block
#define NLB 3125    // logical k_edge blocks (50000/16)
#define CPX 391     // logical blocks per XCD chunk (8*391 = 3128 >= 3125)
#define CAPD 64     // fixed slots per node in ed (P(deg>63) ~ 1e-30 for Poisson(12.8))
#define CCAP 48     // cached entries per node in LDS (slot 0 = self-loop)
#define WSTR 772    // shw row stride: 772 % 32 = 4 -> heads land in distinct banks
#define PLB 2500    // placement blocks (EE/256, 1 edge/thread)

typedef unsigned int uint;
typedef __attribute__((ext_vector_type(8))) short short8;
typedef __attribute__((ext_vector_type(4))) float floatx4;

__device__ inline float2 bf2f(uint u) {
    return make_float2(__uint_as_float(u << 16), __uint_as_float(u & 0xffff0000u));
}
__device__ inline uint packbf(float a, float b) {
    __hip_bfloat162 t;
    t.x = __float2bfloat16(a);
    t.y = __float2bfloat16(b);
    return *(uint*)&t;
}
__device__ inline uint bfbits(float v) {            // bf16 bit pattern (RNE), low 16
    __hip_bfloat16 t = __float2bfloat16(v);
    return (uint)*(unsigned short*)&t;
}
__device__ inline float bflo(uint u) { return __uint_as_float(u << 16); }
__device__ inline float bfhi(uint u) { return __uint_as_float(u & 0xffff0000u); }

// merged prep. Blocks 0..PLB-1: edge placement, 1 edge/thread, SINGLE sweep (the 8x
// grouped sweep cost 34MB extra FETCH for no write benefit — measured r12/r13).
// 8-byte records {src:16 | a0:bf16, a1:bf16 | a2:bf16}. Scatter has a measured
// structural floor (~1 line writeback per store); max MLP is the only lever.
// Then: block PLB -> Mt + zero bns4; +1..+128 -> WbT convert; rest -> node encoder.
__global__ __launch_bounds__(256) void k_prep(const float* __restrict__ lin_e_w,
                                              const float* __restrict__ att_e,
                                              const float* __restrict__ encW,
                                              const float* __restrict__ encB,
                                              const float* __restrict__ W,
                                              const float* __restrict__ x,
                                              const float* __restrict__ nodeW,
                                              const float* __restrict__ nodeB,
                                              const int* __restrict__ src,
                                              const int* __restrict__ dst,
                                              const float* __restrict__ edge_attr,
                                              int* __restrict__ cnt, uint* __restrict__ ed,
                                              float* __restrict__ Mt, float* __restrict__ bns4,
                                              uint* __restrict__ WbT, uint* __restrict__ hb) {
    int tid = threadIdx.x;
    int blk = blockIdx.x;
    if (blk < PLB) {
        int e = blk * 256 + tid;                  // EE = 2500*256 exactly
        int d = dst[e];
        int s = src[e];
        const float* ar = edge_attr + (size_t)e * 3;
        uint w0 = (uint)(s & 0xffff) | (bfbits(ar[0]) << 16);
        uint w1 = bfbits(ar[1]) | (bfbits(ar[2]) << 16);
        int p = atomicAdd(&cnt[d], 1);
        if (p < CAPD)
            *(uint2*)(ed + ((size_t)d * CAPD + p) * 2) = make_uint2(w0, w1);
    } else if (blk == PLB) {
        __shared__ float we[128 * 16];
        for (int idx = tid; idx < 2048; idx += 256) {
            int k = idx >> 4, lh = idx & 15, l = lh >> 2, h = lh & 3;
            const float* wrow = lin_e_w + l * 16384 + k * 128 + h * 32;
            const float* arow = att_e + l * 128 + h * 32;
            float acc = 0.f;
#pragma unroll
            for (int c = 0; c < 32; c++) acc += wrow[c] * arow[c];
            we[k * 16 + lh] = acc;
        }
        for (int i = tid; i < 4 * 8 * 256; i += 256) bns4[i] = 0.f;
        __syncthreads();
        if (tid < 64) {
            int lh = tid >> 2, r = tid & 3;
            float acc = 0.f;
            for (int k = 0; k < 128; k++) {
                float a = (r < 3) ? encW[r * 128 + k] : encB[k];
                acc += a * we[k * 16 + lh];
            }
            Mt[lh * 4 + r] = acc;
        }
    } else if (blk <= PLB + 128) {
        int idx = (blk - PLB - 1) * 256 + tid;    // < 4*128*64 = 32768
        int l = idx >> 13, rem = idx & 8191, n = rem >> 6, u = rem & 63;
        const float* Wl = W + l * 16384;
        WbT[idx] = packbf(Wl[(2 * u) * 128 + n], Wl[(2 * u + 1) * 128 + n]);
    } else {
        int idx = (blk - PLB - 129) * 256 + tid;  // < NN*64 = 3,200,000
        int n = idx >> 6, c0 = (idx & 63) * 2;
        float a0 = nodeB[c0], a1 = nodeB[c0 + 1];
        const float* xr = x + n * 8;
#pragma unroll
        for (int f = 0; f < 8; f++) {
            a0 += xr[f] * nodeW[f * 128 + c0];
            a1 += xr[f] * nodeW[f * 128 + c0 + 1];
        }
        hb[idx] = packbf(a0, a1);
    }
}

// MFMA GEMM with fused BN+ReLU+residual prologue (modes: 0 = read hb as-is (layer 0);
// 1 = h = relu(bn(gout)), write hb; 2 = h = hb + relu(bn(gout)), write hb).
__global__ __launch_bounds__(256) void k_gemm(uint* __restrict__ hb, const uint* __restrict__ gout,
                                              const float* __restrict__ bns,
                                              const float* __restrict__ gamma,
                                              const float* __restrict__ beta,
                                              const uint* __restrict__ WbT,
                                              const float* __restrict__ a_src, const float* __restrict__ a_dst,
                                              uint* __restrict__ xpb, float* __restrict__ s_arr,
                                              float* __restrict__ d_arr, int mode) {
    __shared__ __align__(16) uint Bl[128 * 68];
    __shared__ __align__(16) uint Ah[64 * 66];
    __shared__ float sc[128], sf[128];
    int tid = threadIdx.x;
    int rowBase = blockIdx.x * 64;
    for (int idx = tid; idx < 2048; idx += 256) {
        int n = idx >> 4, u4 = idx & 15;
        uint4 v = *(const uint4*)(WbT + n * 64 + u4 * 4);
        *(uint4*)(&Bl[n * 68 + u4 * 4]) = v;
    }
    if (mode && tid < 128) {
        float s = 0.f, q = 0.f;
#pragma unroll
        for (int k = 0; k < 8; k++) { s += bns[k * 256 + tid]; q += bns[k * 256 + 128 + tid]; }
        float mu = s * (1.f / NN);
        float var = q * (1.f / NN) - mu * mu;
        float iv = rsqrtf(fmaxf(var, 0.f) + 1e-5f);
        float a = gamma[tid] * iv;
        sc[tid] = a;
        sf[tid] = beta[tid] - mu * a;
    }
    __syncthreads();
    if (mode) {
        for (int idx = tid; idx < 4096; idx += 256) {
            int row = idx >> 6, u = idx & 63;
            int gr = rowBase + row;
            uint pk = 0;
            if (gr < NN) {
                float2 v = bf2f(gout[(size_t)gr * 64 + u]);
                int c0 = u * 2;
                float r0 = fmaxf(v.x * sc[c0] + sf[c0], 0.f);
                float r1 = fmaxf(v.y * sc[c0 + 1] + sf[c0 + 1], 0.f);
                if (mode == 2) {
                    float2 hp = bf2f(hb[(size_t)gr * 64 + u]);
                    r0 += hp.x; r1 += hp.y;
                }
                pk = packbf(r0, r1);
                hb[(size_t)gr * 64 + u] = pk;
            }
            Ah[row * 66 + u] = pk;
        }
        __syncthreads();
    }
    int lane = tid & 63, wv = tid >> 6;
    int ln15 = lane & 15, quad = lane >> 4;
    int rowL = wv * 16 + ln15;
    int rowA = rowBase + rowL;
    short8 af[4];
    if (mode) {
#pragma unroll
        for (int c = 0; c < 4; c++)
            af[c] = *(const short8*)((const short*)&Ah[rowL * 66] + c * 32 + quad * 8);
    } else {
        int rowAc = rowA < NN ? rowA : 0;
#pragma unroll
        for (int c = 0; c < 4; c++)
            af[c] = *(const short8*)((const short*)hb + (size_t)rowAc * 128 + c * 32 + quad * 8);
    }
    floatx4 acc[8];
#pragma unroll
    for (int t = 0; t < 8; t++) acc[t] = (floatx4){0.f, 0.f, 0.f, 0.f};
#pragma unroll
    for (int c = 0; c < 4; c++) {
#pragma unroll
        for (int t = 0; t < 8; t++) {
            short8 bf = *(const short8*)((const short*)&Bl[(16 * t + ln15) * 68] + c * 32 + quad * 8);
            acc[t] = __builtin_amdgcn_mfma_f32_16x16x32_bf16(af[c], bf, acc[t], 0, 0, 0);
        }
    }
#pragma unroll
    for (int t = 0; t < 8; t++) {
#pragma unroll
        for (int r = 0; r < 4; r++) {
            float v = acc[t][r];
            float vhi = __shfl_xor(v, 1);
            int grow = rowBase + wv * 16 + quad * 4 + r;
            if (!(ln15 & 1) && grow < NN)
                xpb[(size_t)grow * 64 + 8 * t + (ln15 >> 1)] = packbf(v, vhi);
        }
    }
    float asl[4], ash[4], adl[4], adh[4];
#pragma unroll
    for (int hh = 0; hh < 4; hh++) {
        asl[hh] = a_src[hh * 32 + ln15]; ash[hh] = a_src[hh * 32 + 16 + ln15];
        adl[hh] = a_dst[hh * 32 + ln15]; adh[hh] = a_dst[hh * 32 + 16 + ln15];
    }
#pragma unroll
    for (int r = 0; r < 4; r++) {
        float s0 = acc[0][r] * asl[0] + acc[1][r] * ash[0];
        float s1 = acc[2][r] * asl[1] + acc[3][r] * ash[1];
        float s2 = acc[4][r] * asl[2] + acc[5][r] * ash[2];
        float s3 = acc[6][r] * asl[3] + acc[7][r] * ash[3];
        float d0 = acc[0][r] * adl[0] + acc[1][r] * adh[0];
        float d1 = acc[2][r] * adl[1] + acc[3][r] * adh[1];
        float d2 = acc[4][r] * adl[2] + acc[5][r] * adh[2];
        float d3 = acc[6][r] * adl[3] + acc[7][r] * adh[3];
#pragma unroll
        for (int off = 1; off < 16; off <<= 1) {
            s0 += __shfl_xor(s0, off); s1 += __shfl_xor(s1, off);
            s2 += __shfl_xor(s2, off); s3 += __shfl_xor(s3, off);
            d0 += __shfl_xor(d0, off); d1 += __shfl_xor(d1, off);
            d2 += __shfl_xor(d2, off); d3 += __shfl_xor(d3, off);
        }
        int grow = rowBase + wv * 16 + quad * 4 + r;
        if (ln15 == 0 && grow < NN) {
            *(float4*)(s_arr + grow * 4) = make_float4(s0, s1, s2, s3);
            *(float4*)(d_arr + grow * 4) = make_float4(d0, d1, d2, d3);
        }
    }
}

// fused segment softmax + aggregation + BN-stat partials, v6 (8-byte slot records).
__global__ __launch_bounds__(256) void k_edge(const int* __restrict__ cnt, const uint* __restrict__ ed,
                                              const float* __restrict__ Mt,
                                              const float* __restrict__ s_arr, const float* __restrict__ d_arr,
                                              const uint* __restrict__ xpb, uint* __restrict__ outb,
                                              float* __restrict__ bns, int layer) {
    __shared__ int kc_sh[NPB];
    __shared__ float d4c[NPB][4];
    __shared__ __align__(16) float shw[4][WSTR];   // per-node stripes of CCAP entries
    __shared__ int shs[NPB * CCAP];
    int tid = threadIdx.x;
    int lb = (blockIdx.x & 7) * CPX + (blockIdx.x >> 3);
    if (lb >= NLB) return;
    int nb0 = lb * NPB;
    if (tid < NPB) {
        int c = cnt[nb0 + tid];
        kc_sh[tid] = c < CAPD ? c : CAPD;
    }
    if (tid < NPB * 4)
        d4c[tid >> 2][tid & 3] = d_arr[(size_t)(nb0 + (tid >> 2)) * 4 + (tid & 3)];
    float4 mt0 = *(const float4*)(Mt + (layer * 4 + 0) * 4);
    float4 mt1 = *(const float4*)(Mt + (layer * 4 + 1) * 4);
    float4 mt2 = *(const float4*)(Mt + (layer * 4 + 2) * 4);
    float4 mt3 = *(const float4*)(Mt + (layer * 4 + 3) * 4);
    __syncthreads();
    // ---- pass 1: ni = tid>>4 (node stripe), sub = tid&15
    {
        int ni = tid >> 4, sub = tid & 15;
        int node = nb0 + ni;
        int k = kc_sh[ni];
        float as0 = 0.f, as1 = 0.f, as2 = 0.f;
        float dv0 = d4c[ni][0], dv1 = d4c[ni][1], dv2 = d4c[ni][2], dv3 = d4c[ni][3];
        for (int j = sub; j < k; j += 16) {
            uint2 r = *(const uint2*)(ed + ((size_t)node * CAPD + j) * 2);
            int sv = r.x & 0xffff;
            float a0 = bfhi(r.x), a1 = bflo(r.y), a2 = bfhi(r.y);
            as0 += a0; as1 += a1; as2 += a2;
            float4 s4 = *(const float4*)(s_arr + (size_t)sv * 4);
            float e_0 = a0 * mt0.x + a1 * mt0.y + a2 * mt0.z + mt0.w;
            float e_1 = a0 * mt1.x + a1 * mt1.y + a2 * mt1.z + mt1.w;
            float e_2 = a0 * mt2.x + a1 * mt2.y + a2 * mt2.z + mt2.w;
            float e_3 = a0 * mt3.x + a1 * mt3.y + a2 * mt3.z + mt3.w;
            float al0 = s4.x + dv0 + e_0; al0 = al0 > 0.f ? al0 : 0.2f * al0;
            float al1 = s4.y + dv1 + e_1; al1 = al1 > 0.f ? al1 : 0.2f * al1;
            float al2 = s4.z + dv2 + e_2; al2 = al2 > 0.f ? al2 : 0.2f * al2;
            float al3 = s4.w + dv3 + e_3; al3 = al3 > 0.f ? al3 : 0.2f * al3;
            if (j < CCAP - 1) {
                int ls = ni * CCAP + 1 + j;
                shs[ls] = sv;
                shw[0][ls] = __expf(al0);
                shw[1][ls] = __expf(al1);
                shw[2][ls] = __expf(al2);
                shw[3][ls] = __expf(al3);
            }
        }
#pragma unroll
        for (int off = 8; off; off >>= 1) {
            as0 += __shfl_xor(as0, off, 16);
            as1 += __shfl_xor(as1, off, 16);
            as2 += __shfl_xor(as2, off, 16);
        }
        if (sub == 0) {
            float inv = 1.f / fmaxf((float)k, 1.f);
            float m0 = as0 * inv, m1 = as1 * inv, m2 = as2 * inv;
            float wf = k > 0 ? 1.f : 0.f;
            float4 sl = *(const float4*)(s_arr + (size_t)node * 4);
            float e_0 = m0 * mt0.x + m1 * mt0.y + m2 * mt0.z + wf * mt0.w;
            float e_1 = m0 * mt1.x + m1 * mt1.y + m2 * mt1.z + wf * mt1.w;
            float e_2 = m0 * mt2.x + m1 * mt2.y + m2 * mt2.z + wf * mt2.w;
            float e_3 = m0 * mt3.x + m1 * mt3.y + m2 * mt3.z + wf * mt3.w;
            float al0 = sl.x + dv0 + e_0; al0 = al0 > 0.f ? al0 : 0.2f * al0;
            float al1 = sl.y + dv1 + e_1; al1 = al1 > 0.f ? al1 : 0.2f * al1;
            float al2 = sl.z + dv2 + e_2; al2 = al2 > 0.f ? al2 : 0.2f * al2;
            float al3 = sl.w + dv3 + e_3; al3 = al3 > 0.f ? al3 : 0.2f * al3;
            int ls = ni * CCAP;
            shs[ls] = node;
            shw[0][ls] = __expf(al0);
            shw[1][ls] = __expf(al1);
            shw[2][ls] = __expf(al2);
            shw[3][ls] = __expf(al3);
        }
    }
    __syncthreads();
    // ---- pass 2: wave per node group
    int wv = tid >> 6, lane = tid & 63, hh = lane >> 4;
    float4 mth = hh == 0 ? mt0 : hh == 1 ? mt1 : hh == 2 ? mt2 : mt3;
    float bs0 = 0.f, bs1 = 0.f, bq0 = 0.f, bq1 = 0.f;
#pragma unroll
    for (int q = 0; q < 4; q++) {
        int ni = wv * 4 + q;
        int node = nb0 + ni;
        int k = kc_sh[ni];
        int cached = 1 + (k < CCAP - 1 ? k : CCAP - 1);
        int base = ni * CCAP;
        float acc0 = 0.f, acc1 = 0.f, z = 0.f;
        int j = 0;
        for (; j + 8 <= cached; j += 8) {
            float w[8]; int sv[8]; uint xv[8];
#pragma unroll
            for (int u = 0; u < 8; u++) { w[u] = shw[hh][base + j + u]; sv[u] = shs[base + j + u]; }
#pragma unroll
            for (int u = 0; u < 8; u++) xv[u] = xpb[(size_t)sv[u] * 64 + lane];
#pragma unroll
            for (int u = 0; u < 8; u++) {
                z += w[u];
                float2 f = bf2f(xv[u]);
                acc0 += w[u] * f.x; acc1 += w[u] * f.y;
            }
        }
        for (; j + 4 <= cached; j += 4) {
            float w0 = shw[hh][base + j], w1 = shw[hh][base + j + 1];
            float w2 = shw[hh][base + j + 2], w3 = shw[hh][base + j + 3];
            int s0 = shs[base + j], s1 = shs[base + j + 1];
            int s2 = shs[base + j + 2], s3 = shs[base + j + 3];
            uint x0 = xpb[(size_t)s0 * 64 + lane];
            uint x1 = xpb[(size_t)s1 * 64 + lane];
            uint x2 = xpb[(size_t)s2 * 64 + lane];
            uint x3 = xpb[(size_t)s3 * 64 + lane];
            z += w0 + w1 + w2 + w3;
            float2 f0 = bf2f(x0), f1 = bf2f(x1), f2 = bf2f(x2), f3 = bf2f(x3);
            acc0 += w0 * f0.x + w1 * f1.x + w2 * f2.x + w3 * f3.x;
            acc1 += w0 * f0.y + w1 * f1.y + w2 * f2.y + w3 * f3.y;
        }
        for (; j < cached; j++) {
            float w = shw[hh][base + j];
            int sv = shs[base + j];
            z += w;
            float2 f = bf2f(xpb[(size_t)sv * 64 + lane]);
            acc0 += w * f.x; acc1 += w * f.y;
        }
        for (int je = CCAP - 1; je < k; je++) {    // overflow: plain edges (self-loop cached)
            uint2 r = *(const uint2*)(ed + ((size_t)node * CAPD + je) * 2);
            int sv = r.x & 0xffff;
            float a0 = bfhi(r.x), a1 = bflo(r.y), a2 = bfhi(r.y);
            float sva = s_arr[(size_t)sv * 4 + hh];
            float ev = a0 * mth.x + a1 * mth.y + a2 * mth.z + mth.w;
            float a = sva + d4c[ni][hh] + ev; a = a > 0.f ? a : 0.2f * a;
            float w = __expf(a);
            z += w;
            float2 f = bf2f(xpb[(size_t)sv * 64 + lane]);
            acc0 += w * f.x; acc1 += w * f.y;
        }
        float zi = 1.f / (z + 1e-16f);
        float o0 = acc0 * zi, o1 = acc1 * zi;
        outb[(size_t)node * 64 + lane] = packbf(o0, o1);
        bs0 += o0; bs1 += o1; bq0 += o0 * o0; bq1 += o1 * o1;
    }
    __syncthreads();
    float* scratch = &shw[0][0];
    scratch[wv * 256 + lane * 4 + 0] = bs0;
    scratch[wv * 256 + lane * 4 + 1] = bs1;
    scratch[wv * 256 + lane * 4 + 2] = bq0;
    scratch[wv * 256 + lane * 4 + 3] = bq1;
    __syncthreads();
    float v = scratch[tid] + scratch[256 + tid] + scratch[512 + tid] + scratch[768 + tid];
    int ln = tid >> 2, st = tid & 3;
    int gidx = (st < 2) ? (2 * ln + st) : (128 + 2 * ln + (st - 2));
    atomicAdd(&bns[(blockIdx.x & 7) * 256 + gidx], v);
}

// fused tail: final BN+ReLU+residual computed on the fly -> mean pool -> 3-layer MLP
__global__ __launch_bounds__(256) void k_tail(const uint* __restrict__ hb, const uint* __restrict__ gout,
                                              const float* __restrict__ bns,
                                              const float* __restrict__ gamma, const float* __restrict__ beta,
                                              const int* __restrict__ batch,
                                              const float* __restrict__ w1, const float* __restrict__ b1,
                                              const float* __restrict__ w2, const float* __restrict__ b2,
                                              const float* __restrict__ w3, const float* __restrict__ b3,
                                              float* __restrict__ out) {
    __shared__ float sc[128], sf[128];
    __shared__ float sh[2][256];
    __shared__ float gv[128], h1[128], h2[64];
    int tid = threadIdx.x;
    if (tid < 128) {
        float s = 0.f, q = 0.f;
#pragma unroll
        for (int k = 0; k < 8; k++) { s += bns[k * 256 + tid]; q += bns[k * 256 + 128 + tid]; }
        float mu = s * (1.f / NN);
        float var = q * (1.f / NN) - mu * mu;
        float iv = rsqrtf(fmaxf(var, 0.f) + 1e-5f);
        float a = gamma[tid] * iv;
        sc[tid] = a;
        sf[tid] = beta[tid] - mu * a;
    }
    __syncthreads();
    int gi = blockIdx.x;
    int t = tid & 63, rh = tid >> 6;
    int lo = 0, hi = NN;
    while (lo < hi) { int mid = (lo + hi) >> 1; if (batch[mid] < gi) lo = mid + 1; else hi = mid; }
    int start = lo;
    hi = NN;
    while (lo < hi) { int mid = (lo + hi) >> 1; if (batch[mid] < gi + 1) lo = mid + 1; else hi = mid; }
    int end = lo;
    float s0 = 0.f, s1 = 0.f;
    int c0 = t * 2;
    float a0c = sc[c0], a1c = sc[c0 + 1], f0c = sf[c0], f1c = sf[c0 + 1];
    for (int n = start + rh; n < end; n += 4) {
        float2 gvv = bf2f(gout[(size_t)n * 64 + t]);
        float2 hp = bf2f(hb[(size_t)n * 64 + t]);
        s0 += hp.x + fmaxf(gvv.x * a0c + f0c, 0.f);
        s1 += hp.y + fmaxf(gvv.y * a1c + f1c, 0.f);
    }
    sh[0][tid] = s0; sh[1][tid] = s1;
    __syncthreads();
    if (rh == 0) {
        float inv = 1.f / fmaxf((float)(end - start), 1.f);
        gv[2 * t]     = (sh[0][t] + sh[0][64 + t] + sh[0][128 + t] + sh[0][192 + t]) * inv;
        gv[2 * t + 1] = (sh[1][t] + sh[1][64 + t] + sh[1][128 + t] + sh[1][192 + t]) * inv;
    }
    __syncthreads();
    if (tid < 128) {
        float acc = b1[tid];
        for (int kk = 0; kk < 128; kk++) acc += gv[kk] * w1[kk * 128 + tid];
        h1[tid] = fmaxf(acc, 0.f);
    }
    __syncthreads();
    if (tid < 64) {
        float a2 = b2[tid];
        for (int kk = 0; kk < 128; kk++) a2 += h1[kk] * w2[kk * 64 + tid];
        h2[tid] = fmaxf(a2, 0.f);
    }
    __syncthreads();
    if (tid < 64) {
        float p = h2[tid] * w3[tid];
#pragma unroll
        for (int off = 32; off; off >>= 1) p += __shfl_xor(p, off);
        if (tid == 0) out[gi] = p + b3[0];
    }
}

extern "C" void kernel_launch(void* const* d_in, const int* in_sizes, int n_in,
                              void* d_out, int out_size, void* d_ws, size_t ws_size,
                              hipStream_t stream) {
    const float* x            = (const float*)d_in[0];
    const float* edge_attr    = (const float*)d_in[1];
    const int*   edge_index   = (const int*)d_in[2];
    const int*   batch        = (const int*)d_in[3];
    const float* enc_node_w   = (const float*)d_in[4];
    const float* enc_node_b   = (const float*)d_in[5];
    const float* enc_edge_w   = (const float*)d_in[6];
    const float* enc_edge_b   = (const float*)d_in[7];
    const float* gat_lin_w    = (const float*)d_in[8];
    const float* gat_att_src  = (const float*)d_in[9];
    const float* gat_att_dst  = (const float*)d_in[10];
    const float* gat_lin_edge = (const float*)d_in[11];
    const float* gat_att_edge = (const float*)d_in[12];
    // d_in[13] = gat_bias: constant per channel before training-mode BN -> cancels, unused
    const float* bn_gamma     = (const float*)d_in[14];
    const float* bn_beta      = (const float*)d_in[15];
    const float* fc1_w        = (const float*)d_in[16];
    const float* fc1_b        = (const float*)d_in[17];
    const float* fc2_w        = (const float*)d_in[18];
    const float* fc2_b        = (const float*)d_in[19];
    const float* fc3_w        = (const float*)d_in[20];
    const float* fc3_b        = (const float*)d_in[21];
    float* outv = (float*)d_out;

    char* ws = (char*)d_ws;
    size_t off = 0;
    auto alloc = [&](size_t bytes) -> void* {
        void* p = ws + off;
        off = (off + bytes + 255) & ~(size_t)255;
        return p;
    };
    uint*  hbv     = (uint*)alloc((size_t)NN * 64 * 4);     // bf16-packed residual stream h
    uint*  goutb   = (uint*)alloc((size_t)NN * 64 * 4);     // bf16-packed GAT output
    uint*  xpb     = (uint*)alloc((size_t)NN * 64 * 4);     // bf16-packed xp
    float* s_arr   = (float*)alloc((size_t)NN * 4 * 4);
    float* d_arr   = (float*)alloc((size_t)NN * 4 * 4);
    int*   cnt     = (int*)alloc((size_t)NN * 4);
    uint*  ed      = (uint*)alloc((size_t)NN * CAPD * 8);   // 8B slot records
    uint*  WbT     = (uint*)alloc((size_t)4 * 128 * 64 * 4);
    float* Mt      = (float*)alloc(64 * 4);
    float* bns4    = (float*)alloc((size_t)4 * 8 * 256 * 4); // 4 layers x 8 XCD copies x 256
    (void)ws_size; (void)in_sizes; (void)n_in; (void)out_size;

    hipMemsetAsync(cnt, 0, NN * 4, stream);

    const int* srce = edge_index;
    const int* dste = edge_index + EE;

    k_prep<<<PLB + 129 + (NN * 64) / 256, 256, 0, stream>>>(
        gat_lin_edge, gat_att_edge, enc_edge_w, enc_edge_b, gat_lin_w,
        x, enc_node_w, enc_node_b, srce, dste, edge_attr,
        cnt, ed, Mt, bns4, WbT, hbv);

    int gemmBlocks = (NN + 63) / 64;
    for (int l = 0; l < 4; l++) {
        int mode = (l == 0) ? 0 : (l == 1 ? 1 : 2);
        const float* bnsPrev = bns4 + (l - 1) * 2048;        // unused when mode==0
        k_gemm<<<gemmBlocks, 256, 0, stream>>>(hbv, goutb,
                                               mode ? bnsPrev : bns4,
                                               bn_gamma + (l ? (l - 1) * 128 : 0),
                                               bn_beta + (l ? (l - 1) * 128 : 0),
                                               WbT + l * 8192,
                                               gat_att_src + l * 128, gat_att_dst + l * 128,
                                               xpb, s_arr, d_arr, mode);
        k_edge<<<8 * CPX, 256, 0, stream>>>(cnt, ed, Mt, s_arr, d_arr, xpb, goutb,
                                            bns4 + l * 2048, l);
    }

    k_tail<<<GG, 256, 0, stream>>>(hbv, goutb, bns4 + 3 * 2048, bn_gamma + 3 * 128,
                                   bn_beta + 3 * 128, batch,
                                   fc1_w, fc1_b, fc2_w, fc2_b, fc3_w, fc3_b, outv);
}